// Round 5
// baseline (490.620 us; speedup 1.0000x reference)
//
#include <hip/hip_runtime.h>
#include <math.h>

#define BSZ 4096
#define NTOK 8192
#define NVEC (BSZ * NTOK / 4)   // 2^23 float4s

#define NBLOCKS 8192
#define NTHREADS 256
#define PER_BLOCK (NVEC / NBLOCKS)   // 1024 float4s per stream per block
#define UNROLL 4

__global__ __launch_bounds__(NTHREADS) void gauss_nll_fused(
    const float4* __restrict__ mu,
    const float4* __restrict__ sigma,
    const float4* __restrict__ ty,
    float* __restrict__ partials,
    unsigned int* __restrict__ counter,
    float* __restrict__ out) {
    int base = blockIdx.x * PER_BLOCK + threadIdx.x;

    float4 m[UNROLL], s[UNROLL], t[UNROLL];
#pragma unroll
    for (int j = 0; j < UNROLL; ++j) m[j] = mu[base + j * NTHREADS];
#pragma unroll
    for (int j = 0; j < UNROLL; ++j) s[j] = sigma[base + j * NTHREADS];
#pragma unroll
    for (int j = 0; j < UNROLL; ++j) t[j] = ty[base + j * NTHREADS];

    float acc = 0.0f;
#pragma unroll
    for (int j = 0; j < UNROLL; ++j) {
        float d0 = t[j].x - m[j].x;
        float d1 = t[j].y - m[j].y;
        float d2 = t[j].z - m[j].z;
        float d3 = t[j].w - m[j].w;
        float r0 = __logf(s[j].x) + d0 * d0 * __builtin_amdgcn_rcpf(s[j].x);
        float r1 = __logf(s[j].y) + d1 * d1 * __builtin_amdgcn_rcpf(s[j].y);
        float r2 = __logf(s[j].z) + d2 * d2 * __builtin_amdgcn_rcpf(s[j].z);
        float r3 = __logf(s[j].w) + d3 * d3 * __builtin_amdgcn_rcpf(s[j].w);
        acc += (r0 + r1) + (r2 + r3);
    }

    // wave-64 butterfly reduce
    for (int off = 32; off > 0; off >>= 1)
        acc += __shfl_down(acc, off, 64);

    __shared__ float wsum[NTHREADS / 64];
    __shared__ int is_last;
    int lane = threadIdx.x & 63;
    int wid = threadIdx.x >> 6;
    if (lane == 0) wsum[wid] = acc;
    __syncthreads();
    if (threadIdx.x == 0) {
        partials[blockIdx.x] = wsum[0] + wsum[1] + wsum[2] + wsum[3];
        __threadfence();  // release: partial visible device-wide before ticket
        unsigned int prev = atomicAdd(counter, 1u);
        is_last = (prev == NBLOCKS - 1);
    }
    __syncthreads();

    if (is_last) {
        __threadfence();  // acquire: see all other blocks' partials
        float a = 0.0f;
        for (int i = threadIdx.x; i < NBLOCKS; i += NTHREADS)
            a += partials[i];  // fixed order -> deterministic
        for (int off = 32; off > 0; off >>= 1)
            a += __shfl_down(a, off, 64);
        __shared__ float fsum[NTHREADS / 64];
        if (lane == 0) fsum[wid] = a;
        __syncthreads();
        if (threadIdx.x == 0) {
            float total = (fsum[0] + fsum[1]) + (fsum[2] + fsum[3]);
            const float log2pi = 1.8378770664093453f;  // log(2*pi)
            out[0] = 0.5f * ((float)NTOK * log2pi + total / (float)BSZ);
        }
    }
}

extern "C" void kernel_launch(void* const* d_in, const int* in_sizes, int n_in,
                              void* d_out, int out_size, void* d_ws, size_t ws_size,
                              hipStream_t stream) {
    const float4* mu = (const float4*)d_in[0];
    const float4* sigma = (const float4*)d_in[1];
    const float4* ty = (const float4*)d_in[2];
    float* out = (float*)d_out;
    float* partials = (float*)d_ws;                       // NBLOCKS floats
    unsigned int* counter = (unsigned int*)((char*)d_ws + NBLOCKS * sizeof(float));

    // zero the arrival counter each call (graph-capture legal, async on stream)
    hipMemsetAsync(counter, 0, sizeof(unsigned int), stream);
    gauss_nll_fused<<<NBLOCKS, NTHREADS, 0, stream>>>(mu, sigma, ty, partials,
                                                      counter, out);
}

// Round 7
// 67.387 us; speedup vs baseline: 7.2807x; 7.2807x over previous
//
#include <hip/hip_runtime.h>
#include <math.h>

#define BSZ 4096
#define NTOK 8192
#define NVEC (BSZ * NTOK / 4)   // 2^23 float4s

#define NBLOCKS 8192
#define NTHREADS 256
#define PER_BLOCK (NVEC / NBLOCKS)   // 1024 float4s per stream per block
#define UNROLL 4

typedef float f32x4 __attribute__((ext_vector_type(4)));

__global__ __launch_bounds__(NTHREADS) void gauss_nll_partial(
    const float4* __restrict__ mu,
    const float4* __restrict__ sigma,
    const float4* __restrict__ ty,
    float* __restrict__ partials) {
    int base = blockIdx.x * PER_BLOCK + threadIdx.x;

    f32x4 m[UNROLL];
    float4 s[UNROLL], t[UNROLL];
    // mu is streamed non-temporally (nt bit): it never earns L3 residency,
    // leaving sigma+ty (2 x 128 MiB = 256 MiB) to fit the Infinity Cache.
    const f32x4* mu_nt = (const f32x4*)mu;
#pragma unroll
    for (int j = 0; j < UNROLL; ++j)
        m[j] = __builtin_nontemporal_load(&mu_nt[base + j * NTHREADS]);
#pragma unroll
    for (int j = 0; j < UNROLL; ++j) s[j] = sigma[base + j * NTHREADS];
#pragma unroll
    for (int j = 0; j < UNROLL; ++j) t[j] = ty[base + j * NTHREADS];

    float acc = 0.0f;
#pragma unroll
    for (int j = 0; j < UNROLL; ++j) {
        float d0 = t[j].x - m[j].x;
        float d1 = t[j].y - m[j].y;
        float d2 = t[j].z - m[j].z;
        float d3 = t[j].w - m[j].w;
        float r0 = __logf(s[j].x) + d0 * d0 * __builtin_amdgcn_rcpf(s[j].x);
        float r1 = __logf(s[j].y) + d1 * d1 * __builtin_amdgcn_rcpf(s[j].y);
        float r2 = __logf(s[j].z) + d2 * d2 * __builtin_amdgcn_rcpf(s[j].z);
        float r3 = __logf(s[j].w) + d3 * d3 * __builtin_amdgcn_rcpf(s[j].w);
        acc += (r0 + r1) + (r2 + r3);
    }

    // wave-64 butterfly reduce
    for (int off = 32; off > 0; off >>= 1)
        acc += __shfl_down(acc, off, 64);

    __shared__ float wsum[NTHREADS / 64];
    int lane = threadIdx.x & 63;
    int wid = threadIdx.x >> 6;
    if (lane == 0) wsum[wid] = acc;
    __syncthreads();
    if (threadIdx.x == 0) {
        partials[blockIdx.x] = wsum[0] + wsum[1] + wsum[2] + wsum[3];
    }
}

__global__ __launch_bounds__(1024) void gauss_nll_final(
    const float* __restrict__ partials, float* __restrict__ out) {
    float acc = 0.0f;
    for (int i = threadIdx.x; i < NBLOCKS; i += 1024)
        acc += partials[i];
    for (int off = 32; off > 0; off >>= 1)
        acc += __shfl_down(acc, off, 64);
    __shared__ float wsum[16];
    int lane = threadIdx.x & 63;
    int wid = threadIdx.x >> 6;
    if (lane == 0) wsum[wid] = acc;
    __syncthreads();
    if (threadIdx.x == 0) {
        float total = 0.0f;
        for (int i = 0; i < 16; ++i) total += wsum[i];
        const float log2pi = 1.8378770664093453f;  // log(2*pi)
        out[0] = 0.5f * ((float)NTOK * log2pi + total / (float)BSZ);
    }
}

extern "C" void kernel_launch(void* const* d_in, const int* in_sizes, int n_in,
                              void* d_out, int out_size, void* d_ws, size_t ws_size,
                              hipStream_t stream) {
    const float4* mu = (const float4*)d_in[0];
    const float4* sigma = (const float4*)d_in[1];
    const float4* ty = (const float4*)d_in[2];
    float* out = (float*)d_out;
    float* partials = (float*)d_ws;  // NBLOCKS floats, fully written each call

    gauss_nll_partial<<<NBLOCKS, NTHREADS, 0, stream>>>(mu, sigma, ty, partials);
    gauss_nll_final<<<1, 1024, 0, stream>>>(partials, out);
}